// Round 15
// baseline (1058.523 us; speedup 1.0000x reference)
//
#include <hip/hip_runtime.h>
#include <hip/hip_fp16.h>
#include <math.h>
#include <stdint.h>

typedef _Float16 f16;
typedef _Float16 h8 __attribute__((ext_vector_type(8)));
typedef float f4 __attribute__((ext_vector_type(4)));

#define TSTEPS 48

#define MFMA(a,b,c) __builtin_amdgcn_mfma_f32_16x16x32_f16((a),(b),(c),0,0,0)

__device__ __forceinline__ float gelu_f(float x) {
  float ax = fabsf(x) * 0.7071067811865475f;
  float t = __builtin_amdgcn_rcpf(1.0f + 0.3275911f * ax);
  float poly = t * (0.254829592f + t * (-0.284496736f + t * (1.421413741f +
               t * (-1.453152027f + t * 1.061405429f))));
  float e = exp2f(-ax * ax * 1.4426950408889634f);
  float er = copysignf(1.0f - poly * e, x);
  return 0.5f * x * (1.0f + er);
}

__device__ __forceinline__ float tanh_f(float x) {
  float e = exp2f(x * 2.885390081777927f);
  return 1.0f - 2.0f * __builtin_amdgcn_rcpf(e + 1.0f);
}

__device__ __forceinline__ void gload_lds16(const void* g, void* l) {
  __builtin_amdgcn_global_load_lds(
      (const __attribute__((address_space(1))) void*)g,
      (__attribute__((address_space(3))) void*)l, 16, 0, 0);
}

// barrier that does NOT drain vmcnt (keeps weight prefetch depth alive).
// LDS visibility needs lgkmcnt(0) only; wbuf is wave-private so vmcnt-backed
// LDS writes never cross waves.
__device__ __forceinline__ void barrier_lds() {
  asm volatile("s_waitcnt lgkmcnt(0)" ::: "memory");
  __builtin_amdgcn_s_barrier();
  __builtin_amdgcn_sched_barrier(0);
}

// ---------------- unified lane-linear weight prep (W1/W2/Wo) ----------------
// Fragment (kk, cf): 16 cols c0=cf*16, 32 k's at kk*32. Lane ln holds 8 f16:
// dst[fragid*512 + ln*8 + e] = src[(kk*32 + (ln>>4)*8 + e) * N + cf*16 + (ln&15)]
__global__ void prep_lin(const float* __restrict__ src, f16* __restrict__ dst,
                         int Kreal, int N, int total) {
  int idx = blockIdx.x * 256 + threadIdx.x;
  if (idx >= total) return;
  int fragid = idx >> 9;
  int within = idx & 511;
  int ln = within >> 3, e = within & 7;
  int nfr = N >> 4;
  int kk = fragid / nfr, cf = fragid - kk * nfr;
  int k = kk * 32 + ((ln >> 4) << 3) + e;
  int n = (cf << 4) + (ln & 15);
  dst[idx] = (f16)((k < Kreal) ? src[k * N + n] : 0.f);
}

// ---------------- unified Wf1+Wf2 chunk stream: 32 chunks x 16KB ----------------
// Consumption order per step: o=0..7  : Wf1 h=0 kk=o   (G1 half0)
//                             o=8..15 : Wf2 h=0 kk2=o-8 (G2 half0)
//                             o=16..23: Wf1 h=1 kk=o-16 (G1 half1)
//                             o=24..31: Wf2 h=1 kk2=o-24 (G2 half1)
// Chunk: 16 lane-linear 1KB frags (frag cf = wave wn: cols [16cf,+16) of the
// 256-col group); lane ln holds 8 f16 of k = 32kk + 8(ln>>4)+e, col +(ln&15).
__global__ void prep_wst(const float* __restrict__ wf1, const float* __restrict__ wf2,
                         f16* __restrict__ dst) {
  int idx = blockIdx.x * 256 + threadIdx.x;    // 262144 total
  if (idx >= 262144) return;
  int c = idx >> 13;            // chunk 0..31
  int w13 = idx & 8191;
  int cf = w13 >> 9;
  int w = idx & 511;
  int ln = w >> 3, e = w & 7;
  int h = c >> 4;               // 0 or 1
  int cc = c & 15;
  int kk = cc & 7;
  float v;
  if (cc < 8) {                 // Wf1 [256][512]: k in [0,256), col 256h+...
    int k = 32 * kk + 8 * (ln >> 4) + e;
    int n = 256 * h + 16 * cf + (ln & 15);
    v = wf1[k * 512 + n];
  } else {                      // Wf2 [512][256]: k in [256h,+256), col 0..255
    int k = 256 * h + 32 * kk + 8 * (ln >> 4) + e;
    int n = 16 * cf + (ln & 15);
    v = wf2[k * 256 + n];
  }
  dst[idx] = (f16)v;
}

// ---------------- feature kernel: fourier + hashgrid + z -> fp16 [B][192] ----
__global__ void feat_kernel(const float* __restrict__ x, const float* __restrict__ z,
                            const float* __restrict__ tables, const int* __restrict__ res,
                            const float* __restrict__ freqs, f16* __restrict__ featsH) {
  __shared__ f16 rowbuf[64][194];
  const int t = threadIdx.x;        // 64 threads
  const int b = blockIdx.x;
  const int i = b * 64 + t;

  float xv = x[i];
  float xn = fminf(fmaxf(xv, 0.f), 1.f);
  f16* dst = rowbuf[t];
  dst[0] = (f16)xn;
  float w2pi = 6.283185307179586f * xn;
  #pragma unroll
  for (int k = 0; k < 32; ++k) {
    float a = w2pi * freqs[k];
    float s, c;
    sincosf(a, &s, &c);
    dst[1 + k]  = (f16)s;
    dst[33 + k] = (f16)c;
  }
  #pragma unroll
  for (int l = 0; l < 8; ++l) {
    int R = res[l];
    int Rm1 = R - 1;
    float tt = xn * (float)Rm1;
    int i0 = (int)tt;
    int i1 = min(i0 + 1, Rm1);
    float w = tt - (float)i0;
    uint32_t lt = (uint32_t)(l * 19349663);
    uint32_t h0 = (((uint32_t)i0 * 73856093u) ^ lt) & 16383u;
    uint32_t h1 = (((uint32_t)i1 * 73856093u) ^ lt) & 16383u;
    const float* e0 = tables + ((size_t)l * 16384 + h0) * 8;
    const float* e1 = tables + ((size_t)l * 16384 + h1) * 8;
    #pragma unroll
    for (int e = 0; e < 8; ++e) {
      float v = e0[e] * (1.f - w) + e1[e] * w;
      dst[65 + l * 8 + e] = (f16)v;
    }
  }
  #pragma unroll
  for (int j = 0; j < 32; ++j) dst[129 + j] = (f16)z[(size_t)i * 32 + j];
  #pragma unroll
  for (int j = 161; j < 192; ++j) dst[j] = (f16)0.f;

  __syncthreads();
  uint32_t* dg = (uint32_t*)(featsH + (size_t)b * 64 * 192);
  for (int idx = t; idx < 64 * 96; idx += 64) {
    int row = idx / 96, o = idx - row * 96;
    dg[idx] = ((const uint32_t*)&rowbuf[row][0])[o];
  }
}

// ---------------- main fused kernel ----------------
// 256 blocks x 1024 threads (16 waves, 4/SIMD). Both Wf1 and Wf2 streamed via
// one unified chunk pipeline (R14-verified mechanism): per chunk each wave
// fires ONE global_load_lds (its own 1KB) into a 4-slot ring, counted
// vmcnt(3) (never drained in-loop; barriers use lgkmcnt only). 32 chunks/step,
// 32%4==0 -> fully static slot indices across steps.
// Per-wave regs: a1[4]+a2[4]=32 acc + ~60 arch ~= 100 <= 128 @ 4 waves/EU.
// Master h = f16 hi (hB) + f16 lo (loB) (R12/R14-verified numerics).
// LDS 160K: hB 32K + loB 32K + uB 32K (u half-tile / feats staging) + wbuf 64K.
__global__ __launch_bounds__(1024)
__attribute__((amdgpu_waves_per_eu(4, 4)))
void fractal_main(
    const f16* __restrict__ featsH,
    const f16* __restrict__ W1L, const f16* __restrict__ W2L,
    const f16* __restrict__ WoL, const f16* __restrict__ Wst,
    const float* __restrict__ b1, const float* __restrict__ b2,
    const float* __restrict__ bf1, const float* __restrict__ bf2,
    const float* __restrict__ bo,
    float* __restrict__ out) {
  extern __shared__ char smem[];
  char* hB   = smem;             // 32KB: h hi [64][256] f16 swz (stride 512B)
  char* loB  = smem + 32768;     // 32KB: h lo
  char* uB   = smem + 65536;     // 32KB: u half [64][256] f16 swz / feats staging
  char* wbuf = smem + 98304;     // 64KB: 4 x 16KB chunk ring

  const int tid = threadIdx.x;
  const int wn  = tid >> 6;          // 0..15
  const int ln  = tid & 63;
  const int r   = ln & 15;
  const int g   = ln >> 4;
  const int sw  = (r & 7) << 4;
  const int g16 = g * 16;
  const int row0 = blockIdx.x * 64;

  const int cH = 16 * wn + r;        // wave's column in N=256 ops
  float b1r = b1[cH], b2r = b2[cH], bf2r = bf2[cH], bor = bo[cH];
  float bf1r[2] = { bf1[cH], bf1[256 + cH] };

  const f16* w1b = W1L + (size_t)wn * 512 + ln * 8;   // frag kk*16+wn : +kk<<13
  const f16* w2b = W2L + (size_t)wn * 512 + ln * 8;
  const f16* wob = WoL + (size_t)wn * 512 + ln * 8;
  const char* wsrc = (const char*)Wst + wn * 1024 + ln * 16;  // +chunk<<14
  char* wdst = wbuf + wn * 1024;                               // +slot<<14
  const char* wcon = wbuf + wn * 1024 + ln * 16;               // +slot<<14

  // ---- stage feats tile into uB (swizzled, row stride 384B) ----
  {
    const char* src = (const char*)featsH + (size_t)row0 * 384;
    for (int i = tid; i < 6144; i += 1024) {
      int row = i / 96;
      int off = (i - row * 96) * 4;
      uint32_t v = *(const uint32_t*)(src + (size_t)i * 4);
      *(uint32_t*)(uB + row * 384 + (off ^ ((row & 7) << 4))) = v;
    }
  }
  __syncthreads();

  const f4 zf = {0.f, 0.f, 0.f, 0.f};

  // ---- layer 1: h1 = gelu(feats @ W1 + b1) -> hB ----
  {
    f4 acc[4];
    #pragma unroll
    for (int mf = 0; mf < 4; ++mf) acc[mf] = zf;
    #pragma unroll
    for (int kk = 0; kk < 6; ++kk) {
      h8 bb = *(const h8*)(w1b + ((size_t)kk << 13));
      #pragma unroll
      for (int mf = 0; mf < 4; ++mf) {
        h8 a = *(const h8*)(uB + (16 * mf + r) * 384 + ((kk * 64 + g16) ^ sw));
        acc[mf] = MFMA(a, bb, acc[mf]);
      }
    }
    __syncthreads();   // uB (feats) reads done before reuse
    #pragma unroll
    for (int mf = 0; mf < 4; ++mf)
      #pragma unroll
      for (int j = 0; j < 4; ++j) {
        float hv = gelu_f(acc[mf][j] + b1r);
        int row = 16 * mf + g * 4 + j;
        *(f16*)(hB + row * 512 + ((cH * 2) ^ ((row & 7) << 4))) = (f16)hv;
      }
  }
  __syncthreads();

  // ---- layer 2: h0 = gelu(h1 @ W2 + b2) -> hB(hi) + loB(lo) ----
  {
    f4 acc[4];
    #pragma unroll
    for (int mf = 0; mf < 4; ++mf) acc[mf] = zf;
    #pragma unroll
    for (int kk = 0; kk < 8; ++kk) {
      h8 bb = *(const h8*)(w2b + ((size_t)kk << 13));
      #pragma unroll
      for (int mf = 0; mf < 4; ++mf) {
        h8 a = *(const h8*)(hB + (16 * mf + r) * 512 + ((kk * 64 + g16) ^ sw));
        acc[mf] = MFMA(a, bb, acc[mf]);
      }
    }
    __syncthreads();   // h1 reads done before overwrite
    #pragma unroll
    for (int mf = 0; mf < 4; ++mf)
      #pragma unroll
      for (int j = 0; j < 4; ++j) {
        float hv = gelu_f(acc[mf][j] + b2r);
        int row = 16 * mf + g * 4 + j;
        int so = (cH * 2) ^ ((row & 7) << 4);
        f16 hi = (f16)hv;
        *(f16*)(hB + row * 512 + so) = hi;
        *(f16*)(loB + row * 512 + so) = (f16)(hv - (float)hi);
      }
  }
  __syncthreads();

  // ---- chunk-ring prologue: issue chunks 0,1,2 ----
  #pragma unroll
  for (int c = 0; c < 3; ++c)
    gload_lds16(wsrc + (c << 14), wdst + (c << 14));

  // ---- 48 fractal steps ----
  #pragma unroll 1
  for (int t = 0; t < TSTEPS; ++t) {
    f4 a2[4];
    #pragma unroll
    for (int mf = 0; mf < 4; ++mf) a2[mf] = zf;

    #pragma unroll
    for (int h = 0; h < 2; ++h) {
      // GEMM1 half h: u_h = gelu(hB @ Wf1[:,256h:+256] + bf1)
      f4 a1[4];
      #pragma unroll
      for (int mf = 0; mf < 4; ++mf) a1[mf] = zf;
      #pragma unroll
      for (int kk = 0; kk < 8; ++kk) {
        const int o = h * 16 + kk;
        gload_lds16(wsrc + (((o + 3) & 31) << 14), wdst + (((o + 3) & 3) << 14));
        asm volatile("s_waitcnt vmcnt(3)" ::: "memory");
        __builtin_amdgcn_sched_barrier(0);
        h8 bb = *(const h8*)(wcon + ((o & 3) << 14));
        #pragma unroll
        for (int mf = 0; mf < 4; ++mf) {
          h8 a = *(const h8*)(hB + (16 * mf + r) * 512 + ((kk * 64 + g16) ^ sw));
          a1[mf] = MFMA(a, bb, a1[mf]);
        }
      }
      // epilogue half: gelu -> uB
      #pragma unroll
      for (int mf = 0; mf < 4; ++mf)
        #pragma unroll
        for (int j = 0; j < 4; ++j) {
          float gv = gelu_f(a1[mf][j] + bf1r[h]);
          int row = 16 * mf + g * 4 + j;
          *(f16*)(uB + row * 512 + ((cH * 2) ^ ((row & 7) << 4))) = (f16)gv;
        }
      barrier_lds();

      // GEMM2 partial: a2 += u_h @ Wf2[256h:+256,:]
      #pragma unroll
      for (int kk = 0; kk < 8; ++kk) {
        const int o = h * 16 + 8 + kk;
        gload_lds16(wsrc + (((o + 3) & 31) << 14), wdst + (((o + 3) & 3) << 14));
        asm volatile("s_waitcnt vmcnt(3)" ::: "memory");
        __builtin_amdgcn_sched_barrier(0);
        h8 bb = *(const h8*)(wcon + ((o & 3) << 14));
        #pragma unroll
        for (int mf = 0; mf < 4; ++mf) {
          h8 a = *(const h8*)(uB + (16 * mf + r) * 512 + ((kk * 64 + g16) ^ sw));
          a2[mf] = MFMA(a, bb, a2[mf]);
        }
      }
      barrier_lds();   // uB reads done before next half overwrites
    }

    // step epilogue: m = hi+lo; h' = 0.5*(m + tanh(a2+bf2)); write hi/lo
    #pragma unroll
    for (int mf = 0; mf < 4; ++mf)
      #pragma unroll
      for (int j = 0; j < 4; ++j) {
        int row = 16 * mf + g * 4 + j;
        int so = (cH * 2) ^ ((row & 7) << 4);
        f16* hp = (f16*)(hB + row * 512 + so);
        f16* lp = (f16*)(loB + row * 512 + so);
        float mval = (float)*hp + (float)*lp;
        float u = tanh_f(a2[mf][j] + bf2r);
        float hn = 0.5f * (mval + u);
        f16 hi = (f16)hn;
        *hp = hi;
        *lp = (f16)(hn - (float)hi);
      }
    barrier_lds();
  }

  // ---- final: out = h @ Wo + bo ----
  {
    f4 acc[4];
    #pragma unroll
    for (int mf = 0; mf < 4; ++mf) acc[mf] = zf;
    #pragma unroll
    for (int kk = 0; kk < 8; ++kk) {
      h8 bb = *(const h8*)(wob + ((size_t)kk << 13));
      #pragma unroll
      for (int mf = 0; mf < 4; ++mf) {
        h8 a = *(const h8*)(hB + (16 * mf + r) * 512 + ((kk * 64 + g16) ^ sw));
        acc[mf] = MFMA(a, bb, acc[mf]);
      }
    }
    #pragma unroll
    for (int mf = 0; mf < 4; ++mf)
      #pragma unroll
      for (int j = 0; j < 4; ++j) {
        int row = row0 + 16 * mf + g * 4 + j;
        out[(size_t)row * 256 + cH] = acc[mf][j] + bor;
      }
  }
}

// ---------------- host launch ----------------
extern "C" void kernel_launch(void* const* d_in, const int* in_sizes, int n_in,
                              void* d_out, int out_size, void* d_ws, size_t ws_size,
                              hipStream_t stream) {
  const float* x      = (const float*)d_in[0];
  const float* z      = (const float*)d_in[1];
  const float* tables = (const float*)d_in[2];
  const float* W1     = (const float*)d_in[3];
  const float* b1     = (const float*)d_in[4];
  const float* W2     = (const float*)d_in[5];
  const float* b2     = (const float*)d_in[6];
  const float* Wf1    = (const float*)d_in[7];
  const float* bf1    = (const float*)d_in[8];
  const float* Wf2    = (const float*)d_in[9];
  const float* bf2    = (const float*)d_in[10];
  const float* Wo     = (const float*)d_in[11];
  const float* bo     = (const float*)d_in[12];
  const int*   res    = (const int*)d_in[13];
  const float* freqs  = (const float*)d_in[14];
  float* out = (float*)d_out;

  char* ws = (char*)d_ws;
  f16* featsH = (f16*)(ws);                 // 16384*192*2 = 6291456
  f16* W1L    = (f16*)(ws + 6291456);       // 98304
  f16* W2L    = (f16*)(ws + 6389760);       // 131072
  f16* WoL    = (f16*)(ws + 6520832);       // 131072
  f16* Wst    = (f16*)(ws + 6651904);       // 524288 (32 x 16KB unified stream)

  prep_lin<<<192, 256, 0, stream>>>(W1, W1L, 161, 256, 96  * 512);
  prep_lin<<<256, 256, 0, stream>>>(W2, W2L, 256, 256, 128 * 512);
  prep_lin<<<256, 256, 0, stream>>>(Wo, WoL, 256, 256, 128 * 512);
  prep_wst<<<1024, 256, 0, stream>>>(Wf1, Wf2, Wst);
  feat_kernel<<<256, 64, 0, stream>>>(x, z, tables, res, freqs, featsH);

  (void)hipFuncSetAttribute((const void*)fractal_main,
                            hipFuncAttributeMaxDynamicSharedMemorySize, 163840);
  fractal_main<<<256, 1024, 163840, stream>>>(featsH, W1L, W2L, WoL, Wst,
                                              b1, b2, bf1, bf2, bo, out);
}